// Round 7
// baseline (280.149 us; speedup 1.0000x reference)
//
#include <hip/hip_runtime.h>
#include <hip/hip_bf16.h>
#include <cstdint>
#include <cstddef>

typedef __bf16 bf16_t;
typedef bf16_t bf16x8 __attribute__((ext_vector_type(8)));
typedef bf16_t bf16x4 __attribute__((ext_vector_type(4)));
typedef float f32x4 __attribute__((ext_vector_type(4)));

#define BN_EPS 1e-5f

// Async global->LDS, 16B per lane (wave-uniform LDS base; lane i -> base+i*16).
__device__ __forceinline__ void async_load16(const bf16_t* g, bf16_t* lds) {
  __builtin_amdgcn_global_load_lds(
      (__attribute__((address_space(1))) uint32_t*)(g),
      (__attribute__((address_space(3))) uint32_t*)(lds),
      16, 0, 0);
}

// ---- Merged prep ------------------------------------------------------------
// blocks 0..16383: x -> bf16 + conv feature + zero outacc (4 rows each)
// blocks 16384..16575: W1/W2 transpose+cast tiles
// blocks 16576..16579: BN fold, w1last, zero tile counters
__global__ void prep_kernel(const float* __restrict__ x, bf16_t* __restrict__ xb,
                            float* __restrict__ convf, float* __restrict__ outacc,
                            const float* __restrict__ W1, const float* __restrict__ W2,
                            const float* b1, const float* g1, const float* be1,
                            const float* m1, const float* v1,
                            const float* b2, const float* g2, const float* be2,
                            const float* m2, const float* v2,
                            bf16_t* __restrict__ W1T, bf16_t* __restrict__ W2T,
                            float* s1, float* t1, float* s2, float* t2,
                            float* w1last, unsigned int* cnt) {
  const int blk = blockIdx.x;
  if (blk < 16384) {
    int lane = threadIdx.x & 63;
    int w = threadIdx.x >> 6;
    int row = blk * 4 + w;
    const float4 v = *(const float4*)(x + (size_t)row * 256 + lane * 4);
    float s = v.x + v.y + v.z + v.w;
    bf16x4 o = {(bf16_t)v.x, (bf16_t)v.y, (bf16_t)v.z, (bf16_t)v.w};
    *(bf16x4*)(xb + (size_t)row * 256 + lane * 4) = o;
#pragma unroll
    for (int off = 32; off >= 1; off >>= 1) s += __shfl_down(s, off);
    if (lane == 0) convf[row] = (s > 0.0f) ? 1.0f : 0.0f;  // mean>0 <=> sum>0
    if (threadIdx.x < 4) outacc[blk * 4 + threadIdx.x] = 0.0f;
  } else if (blk < 16576) {
    const int b = blk - 16384;
    const float* src;
    bf16_t* dst;
    int R, C, bx, by;
    if (b < 64) { src = W1; dst = W1T; R = 256; C = 1024; bx = b & 15; by = b >> 4; }
    else        { src = W2; dst = W2T; R = 1024; C = 512; bx = (b - 64) & 7; by = (b - 64) >> 3; }
    __shared__ bf16_t tile[64][66];
    const int r0 = by * 64, c0 = bx * 64;
    const int tc = threadIdx.x & 63;
    const int tr4 = threadIdx.x >> 6;
#pragma unroll
    for (int i = 0; i < 16; ++i) {
      int r = i * 4 + tr4;
      tile[r][tc] = (bf16_t)src[(size_t)(r0 + r) * C + c0 + tc];  // coalesced read
    }
    __syncthreads();
#pragma unroll
    for (int i = 0; i < 16; ++i) {
      int rr = i * 4 + tr4;
      dst[(size_t)(c0 + rr) * R + r0 + tc] = tile[tc][rr];  // coalesced write
    }
  } else {
    int i = (blk - 16576) * 256 + threadIdx.x;
    if (i < 1024) {
      float s = g1[i] * rsqrtf(v1[i] + BN_EPS);
      s1[i] = s;
      t1[i] = be1[i] - m1[i] * s + b1[i] * s;  // bn(z+b1) = z*s + t
      w1last[i] = W1[256 * 1024 + i];          // conv-feature row (coalesced)
    }
    if (i < 512) {
      float s = g2[i] * rsqrtf(v2[i] + BN_EPS);
      s2[i] = s;
      t2[i] = be2[i] - m2[i] * s + b2[i] * s;
    }
    if (i < 256) cnt[i] = 0u;  // gemm2 per-M-tile completion counters
  }
}

// ---- 256x128-tile GEMM core, BK=64, XOR-swizzled LDS ------------------------
// A [M x K], BT [N x K], both bf16 K-contig. 4 waves; wave w = rows
// [w*64, w*64+64) x 128 cols. LDS tile rows of 64 elems = 128B; 16B chunks
// within a row are placed at slot (c ^ (row&7)) so fragment ds_reads spread
// across all 32 banks (2-way = free) while global fetches stay within the
// same 128B lines (coalescing preserved).
template <int K>
__device__ __forceinline__ void gemm_core_256x128(
    const bf16_t* __restrict__ A, const bf16_t* __restrict__ BT,
    int mTile, int nTile, bf16_t* As, bf16_t* Bs,
    int w, int lane, f32x4 (&acc)[4][8]) {
  const int l15 = lane & 15;
  const int quad = lane >> 4;
  const int r8 = lane >> 3;               // row-in-group 0..7
  const int c8 = (lane & 7) ^ r8;         // swizzled global chunk for this lane
  const int swz = l15 & 7;                // row&7 for fragment reads
  const bf16_t* gA = A + (size_t)(mTile + w * 64 + r8) * K + c8 * 8;
  const bf16_t* gB = BT + (size_t)(nTile + w * 32 + r8) * K + c8 * 8;
  bf16_t* lA = As + (w * 64) * 64;
  bf16_t* lB = Bs + (w * 32) * 64;

  for (int k0 = 0; k0 < K; k0 += 64) {
#pragma unroll
    for (int i = 0; i < 8; ++i)           // A: 64 rows x 64 k
      async_load16(gA + (size_t)(i * 8) * K + k0, lA + (i * 8) * 64);
#pragma unroll
    for (int i = 0; i < 4; ++i)           // B: 32 rows x 64 k
      async_load16(gB + (size_t)(i * 8) * K + k0, lB + (i * 8) * 64);
    __syncthreads();  // drains vmcnt before barrier

#pragma unroll
    for (int kk = 0; kk < 2; ++kk) {
      bf16x8 af[4], bfr[8];
#pragma unroll
      for (int t = 0; t < 4; ++t)
        af[t] = *(const bf16x8*)(As + (w * 64 + t * 16 + l15) * 64 + ((kk * 4 + quad) ^ swz) * 8);
#pragma unroll
      for (int t = 0; t < 8; ++t)
        bfr[t] = *(const bf16x8*)(Bs + (t * 16 + l15) * 64 + ((kk * 4 + quad) ^ swz) * 8);
#pragma unroll
      for (int ti = 0; ti < 4; ++ti)
#pragma unroll
        for (int tj = 0; tj < 8; ++tj)
          acc[ti][tj] = __builtin_amdgcn_mfma_f32_16x16x32_bf16(af[ti], bfr[tj], acc[ti][tj], 0, 0, 0);
    }
    __syncthreads();
  }
}

// ---- GEMM1: h1 = relu(bn1(xb @ W1T^T + conv rank-1)), bf16 out --------------
__global__ __launch_bounds__(256, 2) void gemm1_kernel(
    const bf16_t* __restrict__ A, const bf16_t* __restrict__ BT,
    const float* __restrict__ sN, const float* __restrict__ tN,
    const float* __restrict__ convf, const float* __restrict__ w1last,
    bf16_t* __restrict__ out) {
  constexpr int K = 256, N = 1024;
  __shared__ __align__(16) bf16_t As[256 * 64];
  __shared__ __align__(16) bf16_t Bs[128 * 64];

  const int b = blockIdx.x;
  const int mTile = ((b >> 6) * 8 + (b & 7)) * 256;  // 256 M-tiles, XCD-grouped
  const int nTile = ((b >> 3) & 7) * 128;            // 8 N-tiles

  const int tid = threadIdx.x;
  const int lane = tid & 63;
  const int w = tid >> 6;
  const int l15 = lane & 15;
  const int quad = lane >> 4;

  f32x4 acc[4][8];
#pragma unroll
  for (int i = 0; i < 4; ++i)
#pragma unroll
    for (int j = 0; j < 8; ++j) {
      f32x4 z = {0.f, 0.f, 0.f, 0.f};
      acc[i][j] = z;
    }

  gemm_core_256x128<K>(A, BT, mTile, nTile, As, Bs, w, lane, acc);

  float sc[8], tc[8], wl[8];
#pragma unroll
  for (int tj = 0; tj < 8; ++tj) {
    int c = nTile + tj * 16 + l15;
    sc[tj] = sN[c];
    tc[tj] = tN[c];
    wl[tj] = w1last[c];
  }
#pragma unroll
  for (int ti = 0; ti < 4; ++ti)
#pragma unroll
    for (int r = 0; r < 4; ++r) {
      int row = mTile + w * 64 + ti * 16 + quad * 4 + r;
      float cf = convf[row];
      size_t base = (size_t)row * N + nTile;
#pragma unroll
      for (int tj = 0; tj < 8; ++tj) {
        float z = acc[ti][tj][r] + cf * wl[tj];
        z = fmaxf(z * sc[tj] + tc[tj], 0.f);
        out[base + tj * 16 + l15] = (bf16_t)z;
      }
    }
}

// ---- GEMM2 + head + fused sigmoid -------------------------------------------
// Per-row partial logits via atomicAdd; the last of the 4 N-blocks of each
// M-tile (same XCD by swizzle) applies bias+sigmoid in-place.
__global__ __launch_bounds__(256, 2) void gemm2_head_kernel(
    const bf16_t* __restrict__ A, const bf16_t* __restrict__ BT,
    const float* __restrict__ sN, const float* __restrict__ tN,
    const float* __restrict__ W3, const float* __restrict__ b3,
    float* __restrict__ outacc, unsigned int* __restrict__ cnt) {
  constexpr int K = 1024;
  __shared__ __align__(16) bf16_t As[256 * 64];
  __shared__ __align__(16) bf16_t Bs[128 * 64];
  __shared__ int isLast;

  const int b = blockIdx.x;
  const int mt = (b >> 5) * 8 + (b & 7);             // M-tile index, XCD-grouped
  const int mTile = mt * 256;
  const int nTile = ((b >> 3) & 3) * 128;            // 4 N-tiles

  const int tid = threadIdx.x;
  const int lane = tid & 63;
  const int w = tid >> 6;
  const int l15 = lane & 15;
  const int quad = lane >> 4;

  f32x4 acc[4][8];
#pragma unroll
  for (int i = 0; i < 4; ++i)
#pragma unroll
    for (int j = 0; j < 8; ++j) {
      f32x4 z = {0.f, 0.f, 0.f, 0.f};
      acc[i][j] = z;
    }

  gemm_core_256x128<K>(A, BT, mTile, nTile, As, Bs, w, lane, acc);

  float sc[8], tc[8], w3c[8];
#pragma unroll
  for (int tj = 0; tj < 8; ++tj) {
    int c = nTile + tj * 16 + l15;
    sc[tj] = sN[c];
    tc[tj] = tN[c];
    w3c[tj] = W3[c];
  }
#pragma unroll
  for (int ti = 0; ti < 4; ++ti)
#pragma unroll
    for (int r = 0; r < 4; ++r) {
      float p = 0.f;
#pragma unroll
      for (int tj = 0; tj < 8; ++tj) {
        float z = fmaxf(acc[ti][tj][r] * sc[tj] + tc[tj], 0.f);
        p += z * w3c[tj];
      }
#pragma unroll
      for (int m = 1; m <= 8; m <<= 1) p += __shfl_xor(p, m);  // reduce 16 col-lanes
      if (l15 == 0)
        atomicAdd(outacc + mTile + w * 64 + ti * 16 + quad * 4 + r, p);
    }

  // Completion: barrier waits (vmcnt drain) for this block's atomics; counter
  // handshake orders across the tile's 4 blocks (same XCD; device-scope atomics).
  __syncthreads();
  if (tid == 0) {
    __threadfence();
    unsigned int old = atomicAdd(&cnt[mt], 1u);
    isLast = (old == 3u) ? 1 : 0;
  }
  __syncthreads();
  if (isLast) {
    __threadfence();
    float z = __hip_atomic_load(&outacc[mTile + tid], __ATOMIC_RELAXED,
                                __HIP_MEMORY_SCOPE_AGENT) + b3[0];
    outacc[mTile + tid] = 1.0f / (1.0f + expf(-z));
  }
}

extern "C" void kernel_launch(void* const* d_in, const int* in_sizes, int n_in,
                              void* d_out, int out_size, void* d_ws, size_t ws_size,
                              hipStream_t stream) {
  const float* x = (const float*)d_in[0];
  const float* W1 = (const float*)d_in[1];
  const float* b1 = (const float*)d_in[2];
  const float* g1 = (const float*)d_in[3];
  const float* be1 = (const float*)d_in[4];
  const float* m1 = (const float*)d_in[5];
  const float* v1 = (const float*)d_in[6];
  const float* W2 = (const float*)d_in[7];
  const float* b2 = (const float*)d_in[8];
  const float* g2 = (const float*)d_in[9];
  const float* be2 = (const float*)d_in[10];
  const float* m2 = (const float*)d_in[11];
  const float* v2 = (const float*)d_in[12];
  const float* W3 = (const float*)d_in[13];
  const float* b3 = (const float*)d_in[14];
  float* out = (float*)d_out;  // doubles as the fp32 logit accumulator

  char* p = (char*)d_ws;
  bf16_t* h1 = (bf16_t*)p;    p += (size_t)65536 * 1024 * 2;  // 128 MB
  bf16_t* xb = (bf16_t*)p;    p += (size_t)65536 * 256 * 2;   // 32 MB
  bf16_t* W1T = (bf16_t*)p;   p += (size_t)1024 * 256 * 2;
  bf16_t* W2T = (bf16_t*)p;   p += (size_t)512 * 1024 * 2;
  float* convf = (float*)p;   p += (size_t)65536 * 4;
  float* w1last = (float*)p;  p += 1024 * 4;
  float* s1 = (float*)p;      p += 1024 * 4;
  float* t1 = (float*)p;      p += 1024 * 4;
  float* s2 = (float*)p;      p += 512 * 4;
  float* t2 = (float*)p;      p += 512 * 4;
  unsigned int* cnt = (unsigned int*)p;  p += 256 * 4;

  prep_kernel<<<16580, 256, 0, stream>>>(x, xb, convf, out,
                                         W1, W2, b1, g1, be1, m1, v1,
                                         b2, g2, be2, m2, v2,
                                         W1T, W2T, s1, t1, s2, t2, w1last, cnt);

  gemm1_kernel<<<2048, 256, 0, stream>>>(xb, W1T, s1, t1, convf, w1last, h1);
  gemm2_head_kernel<<<1024, 256, 0, stream>>>(h1, W2T, s2, t2, W3, b3, out, cnt);
}